// Round 10
// baseline (72.282 us; speedup 1.0000x reference)
//
#include <hip/hip_runtime.h>

// Chamfer loss: B=32, N=M=2048, D=3, fp32 in, scalar fp32 out.
// loss = sum_b [ sum_m min_n d2 + sum_n min_m d2 ] / B
//
// v9 = v7 with a column-split fork probe:
//  - Each block scans half the opposing cloud (1024 pts, 32KB LDS B-frags);
//    grid 2048 = [dir 2][b 32][stripe 8][colhalf 2]; BLOCK=256 (4 waves),
//    RT=2, __launch_bounds__(256,3) (VGPR<=168, no spill risk, 3 waves/SIMD).
//  - Per-block row-mins reconstructed to d2 = max(0, 2*s_min + |q|^2) >= 0
//    IN-BLOCK (max(0,.) monotone => commutes with cross-block min), then
//    combined via uint atomicMin (order-preserving for non-negative floats)
//    into a 512KB ws slab initialized to 0xFF sentinels.
//  - Small reduce kernel sums the 131072 final mins -> out.
// If this halved-scan probe doesn't move dur_us, the kernel is already at
// the harness floor (~47us fills/restore/gaps) -> ROOFLINE.
//
// Score math (validated absmax=0 in v5-v8): s[q][p] = h_p - q.p via
// 32x32x16 bf16 MFMA, split bf16 packing (lo*lo dropped, ~2e-5):
//   A_k = [-qhx,-qhy,-qhz, -qhx,-qhy,-qhz, -qlx,-qly | -qlz, 1, 1, 0...]
//   B_k = [ phx, phy, phz,  plx, ply, plz,  phx, phy |  phz, hh, hl, 0...]
// Both operands use the same assumed lane->k map -> any HW k-permutation
// cancels. C/D: col=lane&31, row=(reg&3)+8*(reg>>2)+4*(lane>>5) (m74/m101).

typedef __attribute__((ext_vector_type(8)))  short bf16x8;
typedef __attribute__((ext_vector_type(16))) float f32x16;
typedef __attribute__((ext_vector_type(4)))  unsigned int u32x4;

constexpr int B_SZ    = 32;
constexpr int NPTS    = 2048;
constexpr int BLOCK   = 256;               // 4 waves
constexpr int STRIPES = 8;                 // 2048 rows / 256 rows-per-block
constexpr int CSPLIT  = 2;                 // column halves
constexpr int CPTS    = NPTS / CSPLIT;     // 1024 pts per block
constexpr int CT      = CPTS / 32;         // 32 col-tiles per block
constexpr int RT      = 2;                 // row-tiles per wave
constexpr int NQ      = 2 * B_SZ * NPTS;   // 131072 query slots

__device__ __forceinline__ unsigned short f2bf(float f) {   // RNE f32->bf16
    unsigned int u = __float_as_uint(f);
    u += 0x7FFFu + ((u >> 16) & 1u);
    return (unsigned short)(u >> 16);
}
__device__ __forceinline__ float bf2f(unsigned short h) {
    return __uint_as_float(((unsigned int)h) << 16);
}
__device__ __forceinline__ unsigned int pk(unsigned short lo, unsigned short hi) {
    return (unsigned int)lo | ((unsigned int)hi << 16);
}

__global__ __launch_bounds__(BLOCK, 3)
void chamfer_main(const float* __restrict__ x, const float* __restrict__ y,
                  unsigned int* __restrict__ ws) {
    __shared__ u32x4 blds[CT * 64];        // 32 KB B-frags; aliased as colm

    const int bid    = blockIdx.x;
    const int ch     = bid & (CSPLIT - 1);
    const int stripe = (bid >> 1) & (STRIPES - 1);
    const int b      = (bid >> 4) & 31;
    const int dir    = bid >> 9;

    const float* q = ((dir == 0) ? x : y) + (size_t)b * NPTS * 3;
    const float* p = ((dir == 0) ? y : x) + (size_t)b * NPTS * 3 + ch * CPTS * 3;

    // ---- Pack B-fragments for this block's 1024-point column half.
    for (int pi = threadIdx.x; pi < CPTS; pi += BLOCK) {
        const float vx = p[pi * 3 + 0], vy = p[pi * 3 + 1], vz = p[pi * 3 + 2];
        const unsigned short hx = f2bf(vx), hy = f2bf(vy), hz = f2bf(vz);
        const unsigned short lx = f2bf(vx - bf2f(hx));
        const unsigned short ly = f2bf(vy - bf2f(hy));
        const unsigned short lz = f2bf(vz - bf2f(hz));
        const float h = 0.5f * fmaf(vx, vx, fmaf(vy, vy, vz * vz));
        const unsigned short hh = f2bf(h);
        const unsigned short hl = f2bf(h - bf2f(hh));
        const int ct = pi >> 5, col = pi & 31;
        u32x4 g0 = {pk(hx, hy), pk(hz, lx), pk(ly, lz), pk(hx, hy)};
        u32x4 g1 = {pk(hz, hh), pk(hl, 0), 0u, 0u};
        blds[ct * 64 + col]      = g0;     // k0..7
        blds[ct * 64 + 32 + col] = g1;     // k8..15
    }

    // ---- Pack this wave's A-fragments (RT row-tiles).
    const int w    = threadIdx.x >> 6;
    const int lane = threadIdx.x & 63;
    const int g    = lane >> 5;
    const int r32  = lane & 31;
    bf16x8 afrag[RT];
    #pragma unroll
    for (int rt = 0; rt < RT; ++rt) {
        const int row = stripe * 256 + w * (RT * 32) + rt * 32 + r32;
        const float vx = q[row * 3 + 0], vy = q[row * 3 + 1], vz = q[row * 3 + 2];
        const unsigned short hx = f2bf(vx) ^ 0x8000, hy = f2bf(vy) ^ 0x8000,
                             hz = f2bf(vz) ^ 0x8000;
        const unsigned short lx = f2bf(vx - bf2f(hx ^ 0x8000)) ^ 0x8000;
        const unsigned short ly = f2bf(vy - bf2f(hy ^ 0x8000)) ^ 0x8000;
        const unsigned short lz = f2bf(vz - bf2f(hz ^ 0x8000)) ^ 0x8000;
        u32x4 fr;
        if (g == 0)
            fr = (u32x4){pk(hx, hy), pk(hz, hx), pk(hy, hz), pk(lx, ly)};
        else
            fr = (u32x4){pk(lz, 0x3F80), pk(0x3F80, 0), 0u, 0u};
        afrag[rt] = __builtin_bit_cast(bf16x8, fr);
    }
    __syncthreads();

    // ---- Scan 32 col-tiles; running min3 into 16-reg accumulators.
    const f32x16 z = {0.f,0.f,0.f,0.f,0.f,0.f,0.f,0.f,
                      0.f,0.f,0.f,0.f,0.f,0.f,0.f,0.f};
    f32x16 rmin[RT];
    #pragma unroll
    for (int rt = 0; rt < RT; ++rt)
        #pragma unroll
        for (int j = 0; j < 16; ++j) rmin[rt][j] = 3.0e38f;

    #pragma unroll 2
    for (int ct = 0; ct < CT; ct += 2) {
        const bf16x8 b0 = __builtin_bit_cast(bf16x8, blds[ct * 64 + lane]);
        const bf16x8 b1 = __builtin_bit_cast(bf16x8, blds[ct * 64 + 64 + lane]);
        #pragma unroll
        for (int rt = 0; rt < RT; ++rt) {
            f32x16 a0 = __builtin_amdgcn_mfma_f32_32x32x16_bf16(afrag[rt], b0, z, 0, 0, 0);
            f32x16 a1 = __builtin_amdgcn_mfma_f32_32x32x16_bf16(afrag[rt], b1, z, 0, 0, 0);
            #pragma unroll
            for (int j = 0; j < 16; ++j)   // v_min3_f32
                rmin[rt][j] = fminf(fminf(a0[j], a1[j]), rmin[rt][j]);
        }
    }

    // ---- Transpose-reduce (aliased over blds): colm = 256 x 32 floats,
    // XOR-rotate swizzle col' = (col+row)&31 -> conflict-free both phases.
    __syncthreads();
    float* colm = (float*)blds;
    #pragma unroll
    for (int rt = 0; rt < RT; ++rt)
        #pragma unroll
        for (int j = 0; j < 16; ++j) {
            const int lr = w * (RT * 32) + rt * 32 + (j & 3) + 8 * (j >> 2) + 4 * g;
            colm[lr * 32 + ((r32 + lr) & 31)] = rmin[rt][j];
        }
    __syncthreads();

    // ---- Thread t: min over 32 col-partials, reconstruct d2 >= 0,
    // combine across column halves with uint atomicMin.
    const int t = threadIdx.x;
    float v[32];
    #pragma unroll
    for (int k = 0; k < 32; ++k) v[k] = colm[t * 32 + ((k + t) & 31)];
    #pragma unroll
    for (int st = 16; st > 0; st >>= 1)
        #pragma unroll
        for (int i = 0; i < st; ++i) v[i] = fminf(v[i], v[i + st]);

    const int grow = stripe * 256 + t;
    const float qx = q[grow * 3 + 0], qy = q[grow * 3 + 1], qz = q[grow * 3 + 2];
    const float q2 = fmaf(qx, qx, fmaf(qy, qy, qz * qz));
    const float d2 = fmaxf(0.0f, fmaf(2.0f, v[0], q2));
    atomicMin(ws + (size_t)(dir * B_SZ + b) * NPTS + grow, __float_as_uint(d2));
}

// Sum 131072 non-negative mins -> out. 128 blocks x 256 thr x float4.
__global__ __launch_bounds__(256)
void chamfer_reduce(const float* __restrict__ ws, float* __restrict__ out) {
    __shared__ float wsum[4];
    const int i = blockIdx.x * 256 + threadIdx.x;
    float4 vv = ((const float4*)ws)[i];
    float s = (vv.x + vv.y) + (vv.z + vv.w);
    #pragma unroll
    for (int off = 32; off > 0; off >>= 1) s += __shfl_down(s, off, 64);
    if ((threadIdx.x & 63) == 0) wsum[threadIdx.x >> 6] = s;
    __syncthreads();
    if (threadIdx.x == 0) {
        float t = (wsum[0] + wsum[1]) + (wsum[2] + wsum[3]);
        atomicAdd(out, t * (1.0f / B_SZ));
    }
}

extern "C" void kernel_launch(void* const* d_in, const int* in_sizes, int n_in,
                              void* d_out, int out_size, void* d_ws, size_t ws_size,
                              hipStream_t stream) {
    const float* x = (const float*)d_in[0];
    const float* y = (const float*)d_in[1];
    float* out = (float*)d_out;
    unsigned int* ws = (unsigned int*)d_ws;

    hipMemsetAsync(out, 0, sizeof(float) * out_size, stream);
    hipMemsetAsync(ws, 0xFF, (size_t)NQ * sizeof(unsigned int), stream);  // sentinels

    chamfer_main<<<2 * B_SZ * STRIPES * CSPLIT, BLOCK, 0, stream>>>(x, y, ws);
    chamfer_reduce<<<NQ / 4 / 256, 256, 0, stream>>>((const float*)ws, out);
}